// Round 10
// baseline (92.766 us; speedup 1.0000x reference)
//
#include <hip/hip_runtime.h>

// Problem dims
#define BN 8
#define BC 128
#define BH 56
#define BW 56
#define HW 3136
#define NTAP 35
// u16 offsets inside ws:
#define WS_WC 71680                   // stage-2 Wc fragments [WS_WC, WS_WC+4096)
#define WS_XP (WS_WC + 4096)          // padded bf16 im2row x
#define XROW 2368                     // u16 per padded row = 74 cols * 32 ch
#define XPLANE (64 * XROW)            // u16 per (n,cc) plane = 64 rows

typedef unsigned short u16;
typedef unsigned int u32;
typedef __bf16 bf16x8 __attribute__((ext_vector_type(8)));
typedef float f32x4 __attribute__((ext_vector_type(4)));

__device__ __forceinline__ u16 f2b(float f) {
    unsigned u = __float_as_uint(f);
    return (u16)((u + 0x7FFFu + ((u >> 16) & 1u)) >> 16);  // RNE
}
__device__ __forceinline__ u32 pack2(float a, float b) {
    return (u32)f2b(a) | ((u32)f2b(b) << 16);
}
__device__ __forceinline__ void dma16(const void* g, void* l) {
    __builtin_amdgcn_global_load_lds(
        (const __attribute__((address_space(1))) u32*)g,
        (__attribute__((address_space(3))) u32*)l, 16, 0, 0);
}

// prep_w: ws[0..71680) = w3 in exact A-frag lane order per (cc,tap);
//         ws[WS_WC..+4096) = Wc = w5@w4 A-frag order per o-tile, K-padded to 32.
__global__ void prep_w(const float* __restrict__ w3, const float* __restrict__ w4,
                       const float* __restrict__ w5, u16* __restrict__ ws)
{
    int i = blockIdx.x * 256 + threadIdx.x;
    if (i < WS_WC) {
        int j = i & 7, lane = (i >> 3) & 63, r = i >> 9;   // r = cc*35+tap
        int tap = r % NTAP, cc = r / NTAP;
        int q = lane >> 4, lm = lane & 15;
        ws[i] = f2b(w3[(lm * BC + cc * 32 + q * 8 + j) * NTAP + tap]);
    } else if (i < WS_WC + 4096) {
        int i2 = i - WS_WC;
        int j = i2 & 7, lane = (i2 >> 3) & 63, ot = i2 >> 9;
        int q = lane >> 4, lm = lane & 15, o = ot * 16 + lm, k = q * 8 + j;
        float s = 0.f;
        if (k < 16)
            for (int c = 0; c < 16; ++c) s += w5[o * 16 + c] * w4[c * 16 + k];
        ws[i] = f2b(s);
    }
}

// prep_x: xpad[n][cc][hp][col][c32] bf16, all h/w zero-padding baked in.
// Block = (n, cc, hp); LDS transpose for coalesced read + coalesced write.
__global__ __launch_bounds__(256) void prep_x(const float* __restrict__ x,
                                              u16* __restrict__ ws)
{
    __shared__ float ls[32][57];    // +1 col pad: 16-way -> conflict-free
    const int b = blockIdx.x;
    const int hp = b & 63, cc = (b >> 6) & 3, n = b >> 8;
    const int tid = threadIdx.x;
    u32* dst = (u32*)(ws + WS_XP + (size_t)((n * 4 + cc) * 64 + hp) * XROW);
    const int gr = hp - 4;

    if ((unsigned)gr >= BH) {            // padded h rows: all zeros
        for (int i = tid; i < XROW / 2; i += 256) dst[i] = 0u;
        return;
    }
    // load 32 ch x 56 w fp32 (float4, coalesced; row base 16B-aligned: 56%4==0)
    for (int i = tid; i < 32 * 14; i += 256) {
        int c = i / 14, w4 = i % 14;
        float4 v = *(const float4*)(x + ((size_t)(n * BC + cc * 32 + c) * BH + gr) * BW + 4 * w4);
        ls[c][4 * w4 + 0] = v.x;
        ls[c][4 * w4 + 1] = v.y;
        ls[c][4 * w4 + 2] = v.z;
        ls[c][4 * w4 + 3] = v.w;
    }
    __syncthreads();
    // write 74 cols x 16 ch-pairs u32, contiguous (coalesced), w-pad zeroed
    for (int i = tid; i < 74 * 16; i += 256) {
        int col = i >> 4, cp = i & 15;
        int gw = col - 9;
        u32 v = 0u;
        if ((unsigned)gw < BW) v = pack2(ls[2 * cp][gw], ls[2 * cp + 1][gw]);
        dst[col * 16 + cp] = v;
    }
}

// Main: block=(n,h), n = bid&7 (XCD swizzle). 4 waves = 4 w-tiles of 16.
// All staging via async global_load_lds dwordx4 (zero VALU repack).
__global__ __launch_bounds__(256) void conv_mfma(
    const u16* __restrict__ wsT, float* __restrict__ out)
{
    __shared__ __align__(16) u16 xs[5][74][32];    // 23,680 B (DMA region, no pad)
    __shared__ __align__(16) u16 wA[NTAP][64][8];  // 35,840 B (DMA region)
    __shared__ __align__(16) u16 y3T[64][40];      //  5,120 B
    // total 64,640 B -> 2 blocks/CU

    const int n = blockIdx.x & 7, h = blockIdx.x >> 3;
    const int tid = threadIdx.x, lane = tid & 63, wv = tid >> 6;
    const int q = lane >> 4, lm = lane & 15, wpos = wv * 16 + lm;

    // one-time: zero y3T k=16..31 (stage-2 K padding)
    for (int i = tid; i < 512; i += 256) {
        int w = i >> 3, d = i & 7;
        ((u32*)&y3T[w][16])[d] = 0u;
    }

    f32x4 acc = {0.f, 0.f, 0.f, 0.f};
    char* xsf = (char*)&xs[0][0][0];
    char* wAf = (char*)&wA[0][0][0];

    for (int cc = 0; cc < 4; ++cc) {
        __syncthreads();   // prior cc's MFMA reads of xs/wA complete

        // xs: 23,680 B = 24 chunks of 1024 B (last: 128 B / 8 lanes).
        // Flat byte bb maps to row r = bb/4736, in-row offset bb%4736;
        // global row = xpad plane row (h + 2r) -- padding pre-baked.
        const u16* xbase = wsT + WS_XP + (size_t)((n * 4 + cc) * 64 + h) * XROW;
        for (int k = wv; k < 24; k += 4) {
            int bb = k * 1024 + lane * 16;
            int r = bb / 4736;
            int off = bb - r * 4736;
            const u16* g = xbase + (size_t)(2 * r) * XROW + (off >> 1);
            if (k < 23 || lane < 8) dma16(g, xsf + bb);
        }
        // wA: 35 chunks of 1024 B, straight frag-ordered copy.
        const u16* wbase = wsT + (size_t)cc * NTAP * 512;
        for (int k = wv; k < NTAP; k += 4)
            dma16(wbase + (size_t)k * 512 + lane * 8, wAf + k * 1024 + lane * 16);

        __syncthreads();   // vmcnt drained per-wave, then barrier: DMAs visible

        #pragma unroll
        for (int t = 0; t < NTAP; ++t) {
            const int kh = t / 7, kw = t % 7;
            bf16x8 a = *(const bf16x8*)&wA[t][lane][0];
            bf16x8 b = *(const bf16x8*)&xs[kh][wpos + 3 * kw][q * 8];
            acc = __builtin_amdgcn_mfma_f32_16x16x32_bf16(a, b, acc, 0, 0, 0);
        }
    }

    // y3 -> LDS bf16 (lane holds y3[co=q*4+r][w=wpos])
    *(u32*)&y3T[wpos][q * 4]     = pack2(acc[0], acc[1]);
    *(u32*)&y3T[wpos][q * 4 + 2] = pack2(acc[2], acc[3]);
    __syncthreads();

    // Stage-2: out[o-tile][w] = Wc x y3; A-frags straight from global (L2-hot).
    bf16x8 bfrag = *(const bf16x8*)&y3T[wpos][q * 8];
    const bool wok = (wpos < BW);
    #pragma unroll
    for (int ot = 0; ot < 8; ++ot) {
        bf16x8 afrag = *(const bf16x8*)(wsT + WS_WC + (size_t)(ot * 64 + lane) * 8);
        f32x4 c2 = {0.f, 0.f, 0.f, 0.f};
        c2 = __builtin_amdgcn_mfma_f32_16x16x32_bf16(afrag, bfrag, c2, 0, 0, 0);
        if (wok) {
            int o = ot * 16 + q * 4;
            float* po = out + ((size_t)(n * BC + o) * BH + h) * BW + wpos;
            po[0]      = c2[0];
            po[HW]     = c2[1];
            po[2 * HW] = c2[2];
            po[3 * HW] = c2[3];
        }
    }
}

extern "C" void kernel_launch(void* const* d_in, const int* in_sizes, int n_in,
                              void* d_out, int out_size, void* d_ws, size_t ws_size,
                              hipStream_t stream)
{
    (void)in_sizes; (void)n_in; (void)out_size; (void)ws_size;
    const float* x  = (const float*)d_in[0];
    const float* w3 = (const float*)d_in[1];
    const float* w4 = (const float*)d_in[2];
    const float* w5 = (const float*)d_in[3];
    u16* ws = (u16*)d_ws;

    prep_w<<<(WS_WC + 4096) / 256, 256, 0, stream>>>(w3, w4, w5, ws);
    prep_x<<<BN * 4 * 64, 256, 0, stream>>>(x, ws);
    conv_mfma<<<BN * BH, 256, 0, stream>>>(ws, (float*)d_out);
}

// Round 11
// 91.892 us; speedup vs baseline: 1.0095x; 1.0095x over previous
//
#include <hip/hip_runtime.h>

// Problem dims
#define BN 8
#define BC 128
#define BH 56
#define BW 56
#define HW 3136
#define NTAP 35
// u16 offsets inside ws:
#define WS_WC 71680                   // stage-2 Wc fragments [WS_WC, WS_WC+4096)
#define WS_XP (WS_WC + 4096)          // padded bf16 im2row x
#define XROW 2368                     // u16 per padded row = 74 cols * 32 ch

typedef unsigned short u16;
typedef unsigned int u32;
typedef __bf16 bf16x8 __attribute__((ext_vector_type(8)));
typedef float f32x4 __attribute__((ext_vector_type(4)));

__device__ __forceinline__ u16 f2b(float f) {
    unsigned u = __float_as_uint(f);
    return (u16)((u + 0x7FFFu + ((u >> 16) & 1u)) >> 16);  // RNE
}
__device__ __forceinline__ u32 pack2(float a, float b) {
    return (u32)f2b(a) | ((u32)f2b(b) << 16);
}
__device__ __forceinline__ void dma16(const void* g, void* l) {
    __builtin_amdgcn_global_load_lds(
        (const __attribute__((address_space(1))) u32*)g,
        (__attribute__((address_space(3))) u32*)l, 16, 0, 0);
}

// prep_all: blocks [0,2048) build padded bf16 im2row x; blocks [2048,2344)
// build frag-ordered w3 + folded Wc (= w5@w4, K zero-padded to 32).
__global__ __launch_bounds__(256) void prep_all(
    const float* __restrict__ x, const float* __restrict__ w3,
    const float* __restrict__ w4, const float* __restrict__ w5,
    u16* __restrict__ ws)
{
    const int b = blockIdx.x;
    const int tid = threadIdx.x;

    if (b >= 2048) {               // ---- weights part
        int i = (b - 2048) * 256 + tid;
        if (i < WS_WC) {
            int j = i & 7, lane = (i >> 3) & 63, r = i >> 9;   // r = cc*35+tap
            int tap = r % NTAP, cc = r / NTAP;
            int q = lane >> 4, lm = lane & 15;
            ws[i] = f2b(w3[(lm * BC + cc * 32 + q * 8 + j) * NTAP + tap]);
        } else if (i < WS_WC + 4096) {
            int i2 = i - WS_WC;
            int j = i2 & 7, lane = (i2 >> 3) & 63, ot = i2 >> 9;
            int q = lane >> 4, lm = lane & 15, o = ot * 16 + lm, k = q * 8 + j;
            float s = 0.f;
            if (k < 16)
                for (int c = 0; c < 16; ++c) s += w5[o * 16 + c] * w4[c * 16 + k];
            ws[i] = f2b(s);
        }
        return;
    }

    // ---- x part: xpad[n][cc][hp][col][c32] bf16, h/w zero-pad baked in.
    __shared__ float ls[32][57];
    const int hp = b & 63, cc = (b >> 6) & 3, n = b >> 8;
    u32* dst = (u32*)(ws + WS_XP + (size_t)((n * 4 + cc) * 64 + hp) * XROW);
    const int gr = hp - 4;

    if ((unsigned)gr >= BH) {
        for (int i = tid; i < XROW / 2; i += 256) dst[i] = 0u;
        return;
    }
    for (int i = tid; i < 32 * 14; i += 256) {
        int c = i / 14, w4i = i % 14;
        float4 v = *(const float4*)(x + ((size_t)(n * BC + cc * 32 + c) * BH + gr) * BW + 4 * w4i);
        ls[c][4 * w4i + 0] = v.x;
        ls[c][4 * w4i + 1] = v.y;
        ls[c][4 * w4i + 2] = v.z;
        ls[c][4 * w4i + 3] = v.w;
    }
    __syncthreads();
    for (int i = tid; i < 74 * 16; i += 256) {
        int col = i >> 4, cp = i & 15;
        int gw = col - 9;
        u32 v = 0u;
        if ((unsigned)gw < BW) v = pack2(ls[2 * cp][gw], ls[2 * cp + 1][gw]);
        dst[col * 16 + cp] = v;
    }
}

// Main: block=(n,h), n = bid&7 (XCD swizzle). 4 waves = 4 w-tiles of 16.
// B-frags from LDS (DMA-staged); A-frags DIRECT FROM GLOBAL (frag-ordered,
// L1/L2-hot) -- no wA in LDS => 28.8 KB LDS => 4-5 blocks/CU (was 2).
__global__ __launch_bounds__(256, 4) void conv_mfma(
    const u16* __restrict__ wsT, float* __restrict__ out)
{
    __shared__ __align__(16) u16 xs[5][74][32];    // 23,680 B (DMA region)
    __shared__ __align__(16) u16 y3T[64][40];      //  5,120 B
    // total 28,800 B

    const int n = blockIdx.x & 7, h = blockIdx.x >> 3;
    const int tid = threadIdx.x, lane = tid & 63, wv = tid >> 6;
    const int q = lane >> 4, lm = lane & 15, wpos = wv * 16 + lm;

    // one-time: zero y3T k=16..31 (stage-2 K padding)
    for (int i = tid; i < 512; i += 256)
        ((u32*)&y3T[i >> 3][16])[i & 7] = 0u;

    f32x4 acc = {0.f, 0.f, 0.f, 0.f};
    char* xsf = (char*)&xs[0][0][0];
    const u16* ap = wsT + (size_t)lane * 8;   // A-frag base for this lane

    for (int cc = 0; cc < 4; ++cc) {
        __syncthreads();   // prior cc's B-reads of xs complete

        // xs: 23,680 B = 24 chunks of 1 KB DMA (last: 128 B / 8 lanes).
        const u16* xbase = wsT + WS_XP + (size_t)((n * 4 + cc) * 64 + h) * XROW;
        for (int k = wv; k < 24; k += 4) {
            int bb = k * 1024 + lane * 16;
            int r = bb / 4736;               // xs row (global row h+2r, pre-padded)
            int off = bb - r * 4736;
            if (k < 23 || lane < 8)
                dma16(xbase + (size_t)(2 * r) * XROW + (off >> 1), xsf + bb);
        }
        __syncthreads();   // DMA drained + visible

        const u16* at = ap + (size_t)cc * NTAP * 512;
        #pragma unroll
        for (int t = 0; t < NTAP; ++t) {
            const int kh = t / 7, kw = t % 7;
            bf16x8 a = *(const bf16x8*)(at + t * 512);            // global, L1-hot
            bf16x8 b = *(const bf16x8*)&xs[kh][wpos + 3 * kw][q * 8];  // LDS
            acc = __builtin_amdgcn_mfma_f32_16x16x32_bf16(a, b, acc, 0, 0, 0);
        }
    }

    // y3 -> LDS bf16 (lane holds y3[co=q*4+r][w=wpos])
    *(u32*)&y3T[wpos][q * 4]     = pack2(acc[0], acc[1]);
    *(u32*)&y3T[wpos][q * 4 + 2] = pack2(acc[2], acc[3]);
    __syncthreads();

    // Stage-2: out[o-tile][w] = Wc x y3; A-frags straight from global.
    bf16x8 bfrag = *(const bf16x8*)&y3T[wpos][q * 8];
    const bool wok = (wpos < BW);
    #pragma unroll
    for (int ot = 0; ot < 8; ++ot) {
        bf16x8 afrag = *(const bf16x8*)(wsT + WS_WC + (size_t)(ot * 64 + lane) * 8);
        f32x4 c2 = {0.f, 0.f, 0.f, 0.f};
        c2 = __builtin_amdgcn_mfma_f32_16x16x32_bf16(afrag, bfrag, c2, 0, 0, 0);
        if (wok) {
            int o = ot * 16 + q * 4;
            float* po = out + ((size_t)(n * BC + o) * BH + h) * BW + wpos;
            po[0]      = c2[0];
            po[HW]     = c2[1];
            po[2 * HW] = c2[2];
            po[3 * HW] = c2[3];
        }
    }
}

extern "C" void kernel_launch(void* const* d_in, const int* in_sizes, int n_in,
                              void* d_out, int out_size, void* d_ws, size_t ws_size,
                              hipStream_t stream)
{
    (void)in_sizes; (void)n_in; (void)out_size; (void)ws_size;
    const float* x  = (const float*)d_in[0];
    const float* w3 = (const float*)d_in[1];
    const float* w4 = (const float*)d_in[2];
    const float* w5 = (const float*)d_in[3];
    u16* ws = (u16*)d_ws;

    prep_all<<<2048 + 296, 256, 0, stream>>>(x, w3, w4, w5, ws);
    conv_mfma<<<BN * BH, 256, 0, stream>>>(ws, (float*)d_out);
}